// Round 12
// baseline (636.089 us; speedup 1.0000x reference)
//
#include <hip/hip_runtime.h>
#include <stdint.h>

#define NN 100000
#define NE 1600000
#define DD 128
#define NG 128
#define NPX 12500     // nodes per XCD partition (8 * 12500 = 100000)
#define NBS 25        // scan blocks: 25 * 4096 > NN+1

using f32x4  = __attribute__((ext_vector_type(4))) float;
using bf16x8 = __attribute__((ext_vector_type(8))) __bf16;

__device__ __forceinline__ unsigned short f2bf(float f) {
  unsigned int u = __builtin_bit_cast(unsigned int, f);
  u = (u + 0x7FFFu + ((u >> 16) & 1u)) >> 16;
  return (unsigned short)u;
}

__device__ __forceinline__ float2 bfu(unsigned int u) {
  float2 r;
  r.x = __builtin_bit_cast(float, u << 16);
  r.y = __builtin_bit_cast(float, u & 0xffff0000u);
  return r;
}

__device__ __forceinline__ void addu4(float* a, uint4 v) {
  float2 p0 = bfu(v.x), p1 = bfu(v.y), p2 = bfu(v.z), p3 = bfu(v.w);
  a[0] += p0.x; a[1] += p0.y; a[2] += p1.x; a[3] += p1.y;
  a[4] += p2.x; a[5] += p2.y; a[6] += p3.x; a[7] += p3.y;
}

union ABu { uint4 q; bf16x8 v; };

// ---------------- CSR build (XCD-partitioned scatter) ----------------
__global__ void k_count(const int* __restrict__ dst, int* __restrict__ deg) {
  int xcd = blockIdx.x & 7;
  int e = (blockIdx.x >> 3) * 256 + threadIdx.x;
  if (e >= NE) return;
  int d = dst[e];
  if ((unsigned)(d - xcd * NPX) < (unsigned)NPX) atomicAdd(&deg[d], 1);
}

// ---- 3-kernel scan: rowptr = exclusive_scan(deg), rowptr[NN] = total ----
__global__ __launch_bounds__(1024) void k_scanA(const int* __restrict__ deg,
                                                int* __restrict__ rowptr,
                                                int* __restrict__ bsum) {
  __shared__ int wsum[16];
  const int tid = threadIdx.x, wid = tid >> 6, lane = tid & 63;
  int idx = blockIdx.x * 4096 + tid * 4;
  int v0 = (idx + 0 < NN) ? deg[idx + 0] : 0;
  int v1 = (idx + 1 < NN) ? deg[idx + 1] : 0;
  int v2 = (idx + 2 < NN) ? deg[idx + 2] : 0;
  int v3 = (idx + 3 < NN) ? deg[idx + 3] : 0;
  int tsum = v0 + v1 + v2 + v3;
  int sc = tsum;
  #pragma unroll
  for (int off = 1; off < 64; off <<= 1) {
    int n = __shfl_up(sc, off);
    if (lane >= off) sc += n;
  }
  if (lane == 63) wsum[wid] = sc;
  __syncthreads();
  if (wid == 0 && lane < 16) {
    int w = wsum[lane];
    #pragma unroll
    for (int off = 1; off < 16; off <<= 1) {
      int n = __shfl_up(w, off);
      if (lane >= off) w += n;
    }
    wsum[lane] = w;
  }
  __syncthreads();
  int excl = (wid ? wsum[wid - 1] : 0) + sc - tsum;
  if (idx     <= NN) rowptr[idx]     = excl;
  if (idx + 1 <= NN) rowptr[idx + 1] = excl + v0;
  if (idx + 2 <= NN) rowptr[idx + 2] = excl + v0 + v1;
  if (idx + 3 <= NN) rowptr[idx + 3] = excl + v0 + v1 + v2;
  if (tid == 1023) bsum[blockIdx.x] = wsum[15];   // block total
}

__global__ void k_scanB(int* __restrict__ bsum) {
  int lane = threadIdx.x & 63;
  int v = (lane < NBS) ? bsum[lane] : 0;
  int sc = v;
  #pragma unroll
  for (int off = 1; off < 64; off <<= 1) {
    int n = __shfl_up(sc, off);
    if (lane >= off) sc += n;
  }
  if (lane < NBS) bsum[lane] = sc - v;   // exclusive
}

__global__ __launch_bounds__(1024) void k_scanC(int* __restrict__ rowptr,
                                                const int* __restrict__ bsum) {
  int add = bsum[blockIdx.x];
  int idx = blockIdx.x * 4096 + threadIdx.x * 4;
  if (idx     <= NN) rowptr[idx]     += add;
  if (idx + 1 <= NN) rowptr[idx + 1] += add;
  if (idx + 2 <= NN) rowptr[idx + 2] += add;
  if (idx + 3 <= NN) rowptr[idx + 3] += add;
}

__global__ void k_fill(const int* __restrict__ src, const int* __restrict__ dst,
                       const int* __restrict__ rowptr, int* __restrict__ cursor,
                       int* __restrict__ csr) {
  int xcd = blockIdx.x & 7;
  int e = (blockIdx.x >> 3) * 256 + threadIdx.x;
  if (e >= NE) return;
  int d = dst[e];
  if ((unsigned)(d - xcd * NPX) < (unsigned)NPX) {
    int pos = rowptr[d] + atomicAdd(&cursor[d], 1);
    csr[pos] = src[e];
  }
}

// ---------------- weight transpose + bf16 convert ----------------
__global__ void k_wconv(const float* __restrict__ w0, const float* __restrict__ w1,
                        const float* __restrict__ w2, const float* __restrict__ w3,
                        const float* __restrict__ w4, const float* __restrict__ w5,
                        unsigned short* __restrict__ wt) {
  int idx = blockIdx.x * 256 + threadIdx.x;
  if (idx >= 6 * 16384) return;
  int m = idx >> 14, rem = idx & 16383;
  int n = rem >> 7, k = rem & 127;
  const float* W = (m == 0) ? w0 : (m == 1) ? w1 : (m == 2) ? w2
                 : (m == 3) ? w3 : (m == 4) ? w4 : w5;
  wt[idx] = f2bf(W[k * 128 + n]);   // wt[m][n][k] = W[k][n]
}

// ---------------- x -> bf16 ----------------
__global__ void k_xconv(const float* __restrict__ x, unsigned short* __restrict__ xb) {
  int i = blockIdx.x * 256 + threadIdx.x;
  if (i >= NN * DD / 4) return;
  float4 v = ((const float4*)x)[i];
  uint2 p;
  p.x = (unsigned int)f2bf(v.x) | ((unsigned int)f2bf(v.y) << 16);
  p.y = (unsigned int)f2bf(v.z) | ((unsigned int)f2bf(v.w) << 16);
  ((uint2*)xb)[i] = p;
}

// ---------------- fused GIN layer: aggregate + MLP ----------------
// 3125 blocks x 128 threads = 2 waves/block; each wave owns 16 nodes with a
// private 4KB LDS half -> zero barriers. (2-wave blocks lift the ~16
// workgroups/CU cap that throttled 1-wave blocks to <=16 waves/CU.)
// Phase 1: lane-group kg gathers row lrow=it*4+kg, 4 rows in flight
// (dwordx4 = 256B row / 16 lanes); fp32 accum; bf16 -> XOR-swizzled tile
// (16B chunk c of row r at c ^ (r&7)). Phase 2: GEMM1, epilogue overwrites
// tile with u, GEMM2, bf16 store.
__global__ __launch_bounds__(128) void k_gin(const unsigned short* __restrict__ hb,
                                             const int* __restrict__ rowptr,
                                             const int* __restrict__ csr,
                                             const unsigned short* __restrict__ w1t,
                                             const float* __restrict__ b1,
                                             const unsigned short* __restrict__ w2t,
                                             const float* __restrict__ b2,
                                             unsigned short* __restrict__ hout) {
  __shared__ unsigned short tl[2][16 * DD];   // 8 KB, one half per wave
  const int wv   = threadIdx.x >> 6;
  const int lane = threadIdx.x & 63;
  const int r16  = lane & 15;
  const int kg   = lane >> 4;
  const int waveBase = blockIdx.x * 32 + wv * 16;
  unsigned short* wt_ = tl[wv];
  const uint4* h4 = (const uint4*)hb;

  // ---- phase 1: aggregate ----
  #pragma unroll
  for (int it = 0; it < 4; ++it) {
    const int lrow = it * 4 + kg;
    const int node = waveBase + lrow;
    float acc[8] = {0.f,0.f,0.f,0.f,0.f,0.f,0.f,0.f};
    if (node < NN) {
      addu4(acc, h4[(size_t)node * 16 + r16]);   // self
      int j = rowptr[node];
      const int je = rowptr[node + 1];
      for (; j + 3 < je; j += 4) {
        int s0 = csr[j], s1 = csr[j + 1], s2 = csr[j + 2], s3 = csr[j + 3];
        uint4 v0 = h4[(size_t)s0 * 16 + r16];
        uint4 v1 = h4[(size_t)s1 * 16 + r16];
        uint4 v2 = h4[(size_t)s2 * 16 + r16];
        uint4 v3 = h4[(size_t)s3 * 16 + r16];
        addu4(acc, v0); addu4(acc, v1); addu4(acc, v2); addu4(acc, v3);
      }
      for (; j < je; ++j) addu4(acc, h4[(size_t)csr[j] * 16 + r16]);
    }
    uint4 p;
    p.x = (unsigned int)f2bf(acc[0]) | ((unsigned int)f2bf(acc[1]) << 16);
    p.y = (unsigned int)f2bf(acc[2]) | ((unsigned int)f2bf(acc[3]) << 16);
    p.z = (unsigned int)f2bf(acc[4]) | ((unsigned int)f2bf(acc[5]) << 16);
    p.w = (unsigned int)f2bf(acc[6]) | ((unsigned int)f2bf(acc[7]) << 16);
    *(uint4*)(wt_ + lrow * DD + ((r16 ^ (lrow & 7)) << 3)) = p;
  }
  // wave-private tile: no barrier needed

  // ---- phase 2a: GEMM1  u = ReLU(t @ W1 + b1) ----
  f32x4 acc[8];
  #pragma unroll
  for (int nb = 0; nb < 8; ++nb) acc[nb] = (f32x4){0.f, 0.f, 0.f, 0.f};
  #pragma unroll
  for (int s = 0; s < 4; ++s) {
    ABu au;
    au.q = *(const uint4*)(wt_ + r16 * DD + ((((s << 2) + kg) ^ (r16 & 7)) << 3));
    #pragma unroll
    for (int nb = 0; nb < 8; ++nb) {
      ABu bu; bu.q = *(const uint4*)(w1t + (nb * 16 + r16) * DD + s * 32 + kg * 8);
      acc[nb] = __builtin_amdgcn_mfma_f32_16x16x32_bf16(au.v, bu.v, acc[nb], 0, 0, 0);
    }
  }
  #pragma unroll
  for (int nb = 0; nb < 8; ++nb) {
    int n = nb * 16 + r16;
    float bias = b1[n];
    #pragma unroll
    for (int reg = 0; reg < 4; ++reg) {
      int urow = (kg << 2) + reg;
      float v = acc[nb][reg] + bias;
      v = v > 0.f ? v : 0.f;
      wt_[urow * DD + ((((n >> 3) ^ (urow & 7)) << 3) | (n & 7))] = f2bf(v);
    }
  }

  // ---- phase 2b: GEMM2  hout = u @ W2 + b2 ----
  #pragma unroll
  for (int nb = 0; nb < 8; ++nb) acc[nb] = (f32x4){0.f, 0.f, 0.f, 0.f};
  #pragma unroll
  for (int s = 0; s < 4; ++s) {
    ABu au;
    au.q = *(const uint4*)(wt_ + r16 * DD + ((((s << 2) + kg) ^ (r16 & 7)) << 3));
    #pragma unroll
    for (int nb = 0; nb < 8; ++nb) {
      ABu bu; bu.q = *(const uint4*)(w2t + (nb * 16 + r16) * DD + s * 32 + kg * 8);
      acc[nb] = __builtin_amdgcn_mfma_f32_16x16x32_bf16(au.v, bu.v, acc[nb], 0, 0, 0);
    }
  }
  #pragma unroll
  for (int reg = 0; reg < 4; ++reg) {
    int row = waveBase + (kg << 2) + reg;
    if (row < NN) {
      #pragma unroll
      for (int nb = 0; nb < 8; ++nb) {
        int n = nb * 16 + r16;
        hout[row * DD + n] = f2bf(acc[nb][reg] + b2[n]);
      }
    }
  }
}

// ---------------- fused pooling: one block per graph (batch sorted) ----------------
__global__ __launch_bounds__(256) void k_pool(const unsigned short* __restrict__ hb,
                                              const int* __restrict__ batch,
                                              float* __restrict__ out) {
  const int g  = blockIdx.x;
  const int f2 = threadIdx.x & 63;
  const int rp = threadIdx.x >> 6;
  int lo = 0, hi = NN;
  while (lo < hi) { int m = (lo + hi) >> 1; if (batch[m] < g) lo = m + 1; else hi = m; }
  const int start = lo;
  hi = NN;
  while (lo < hi) { int m = (lo + hi) >> 1; if (batch[m] < g + 1) lo = m + 1; else hi = m; }
  const int end = lo;

  const unsigned int* h32 = (const unsigned int*)hb;
  float2 acc = {0.f, 0.f};
  int i = start + rp;
  for (; i + 4 < end; i += 8) {
    float2 a = bfu(h32[(size_t)i * 64 + f2]);
    float2 b = bfu(h32[(size_t)(i + 4) * 64 + f2]);
    acc.x += a.x + b.x; acc.y += a.y + b.y;
  }
  for (; i < end; i += 4) {
    float2 a = bfu(h32[(size_t)i * 64 + f2]);
    acc.x += a.x; acc.y += a.y;
  }

  __shared__ float2 part[4][64];
  part[rp][f2] = acc;
  __syncthreads();
  if (rp == 0) {
    float2 t0 = part[0][f2], t1 = part[1][f2], t2 = part[2][f2], t3 = part[3][f2];
    float inv = 1.0f / (float)max(end - start, 1);
    out[g * DD + 2 * f2]     = (t0.x + t1.x + t2.x + t3.x) * inv;
    out[g * DD + 2 * f2 + 1] = (t0.y + t1.y + t2.y + t3.y) * inv;
  }
}

// ---------------- launch ----------------
extern "C" void kernel_launch(void* const* d_in, const int* in_sizes, int n_in,
                              void* d_out, int out_size, void* d_ws, size_t ws_size,
                              hipStream_t stream) {
  const float* x    = (const float*)d_in[0];
  const int* ei     = (const int*)d_in[1];
  const int* src    = ei;
  const int* dst    = ei + NE;
  const int* batch  = (const int*)d_in[2];

  char* ws = (char*)d_ws;
  size_t off = 0;
  auto alloc = [&](size_t bytes) { char* p = ws + off; off = (off + bytes + 255) & ~(size_t)255; return p; };

  int*  deg    = (int*)alloc(2 * NN * 4);       // deg + cursor contiguous
  int*  cursor = deg + NN;
  int*  rowptr = (int*)alloc((NN + 1) * 4);
  int*  bsum   = (int*)alloc(NBS * 4);
  int*  csr    = (int*)alloc(NE * 4);
  unsigned short* wt = (unsigned short*)alloc(6 * 16384 * 2);
  unsigned short* xb = (unsigned short*)alloc((size_t)NN * DD * 2);
  unsigned short* hA = (unsigned short*)alloc((size_t)NN * DD * 2);
  unsigned short* hB = (unsigned short*)alloc((size_t)NN * DD * 2);

  hipMemsetAsync(deg, 0, 2 * NN * 4, stream);

  k_wconv<<<(6 * 16384 + 255) / 256, 256, 0, stream>>>(
      (const float*)d_in[3], (const float*)d_in[5],
      (const float*)d_in[7], (const float*)d_in[9],
      (const float*)d_in[11], (const float*)d_in[13], wt);
  k_xconv<<<(NN * DD / 4 + 255) / 256, 256, 0, stream>>>(x, xb);

  const int echunks = (NE + 255) / 256;
  k_count<<<8 * echunks, 256, 0, stream>>>(dst, deg);
  k_scanA<<<NBS, 1024, 0, stream>>>(deg, rowptr, bsum);
  k_scanB<<<1, 64, 0, stream>>>(bsum);
  k_scanC<<<NBS, 1024, 0, stream>>>(rowptr, bsum);
  k_fill<<<8 * echunks, 256, 0, stream>>>(src, dst, rowptr, cursor, csr);

  const unsigned short* hin = xb;
  unsigned short* houts[3] = {hA, hB, hA};
  for (int l = 0; l < 3; ++l) {
    k_gin<<<(NN + 31) / 32, 128, 0, stream>>>(
        hin, rowptr, csr,
        wt + (2 * l) * 16384, (const float*)d_in[4 + 4 * l],
        wt + (2 * l + 1) * 16384, (const float*)d_in[6 + 4 * l], houts[l]);
    hin = houts[l];
  }

  k_pool<<<NG, 256, 0, stream>>>(hin, batch, (float*)d_out);
}

// Round 13
// 612.502 us; speedup vs baseline: 1.0385x; 1.0385x over previous
//
#include <hip/hip_runtime.h>
#include <stdint.h>

#define NN 100000
#define NE 1600000
#define DD 128
#define NG 128
#define NPX 12500     // nodes per XCD partition (8 * 12500 = 100000)
#define NBS 25        // scan blocks: 25 * 4096 > NN+1

using f32x4  = __attribute__((ext_vector_type(4))) float;
using bf16x8 = __attribute__((ext_vector_type(8))) __bf16;

__device__ __forceinline__ unsigned short f2bf(float f) {
  unsigned int u = __builtin_bit_cast(unsigned int, f);
  u = (u + 0x7FFFu + ((u >> 16) & 1u)) >> 16;
  return (unsigned short)u;
}

__device__ __forceinline__ float2 bfu(unsigned int u) {
  float2 r;
  r.x = __builtin_bit_cast(float, u << 16);
  r.y = __builtin_bit_cast(float, u & 0xffff0000u);
  return r;
}

__device__ __forceinline__ void addu4(float* a, uint4 v) {
  float2 p0 = bfu(v.x), p1 = bfu(v.y), p2 = bfu(v.z), p3 = bfu(v.w);
  a[0] += p0.x; a[1] += p0.y; a[2] += p1.x; a[3] += p1.y;
  a[4] += p2.x; a[5] += p2.y; a[6] += p3.x; a[7] += p3.y;
}

union ABu { uint4 q; bf16x8 v; };

// ---------------- CSR build (XCD-partitioned scatter) ----------------
__global__ void k_count(const int* __restrict__ dst, int* __restrict__ deg) {
  int xcd = blockIdx.x & 7;
  int e = (blockIdx.x >> 3) * 256 + threadIdx.x;
  if (e >= NE) return;
  int d = dst[e];
  if ((unsigned)(d - xcd * NPX) < (unsigned)NPX) atomicAdd(&deg[d], 1);
}

// ---- 3-kernel scan: rowptr = exclusive_scan(deg), rowptr[NN] = total ----
__global__ __launch_bounds__(1024) void k_scanA(const int* __restrict__ deg,
                                                int* __restrict__ rowptr,
                                                int* __restrict__ bsum) {
  __shared__ int wsum[16];
  const int tid = threadIdx.x, wid = tid >> 6, lane = tid & 63;
  int idx = blockIdx.x * 4096 + tid * 4;
  int v0 = (idx + 0 < NN) ? deg[idx + 0] : 0;
  int v1 = (idx + 1 < NN) ? deg[idx + 1] : 0;
  int v2 = (idx + 2 < NN) ? deg[idx + 2] : 0;
  int v3 = (idx + 3 < NN) ? deg[idx + 3] : 0;
  int tsum = v0 + v1 + v2 + v3;
  int sc = tsum;
  #pragma unroll
  for (int off = 1; off < 64; off <<= 1) {
    int n = __shfl_up(sc, off);
    if (lane >= off) sc += n;
  }
  if (lane == 63) wsum[wid] = sc;
  __syncthreads();
  if (wid == 0 && lane < 16) {
    int w = wsum[lane];
    #pragma unroll
    for (int off = 1; off < 16; off <<= 1) {
      int n = __shfl_up(w, off);
      if (lane >= off) w += n;
    }
    wsum[lane] = w;
  }
  __syncthreads();
  int excl = (wid ? wsum[wid - 1] : 0) + sc - tsum;
  if (idx     <= NN) rowptr[idx]     = excl;
  if (idx + 1 <= NN) rowptr[idx + 1] = excl + v0;
  if (idx + 2 <= NN) rowptr[idx + 2] = excl + v0 + v1;
  if (idx + 3 <= NN) rowptr[idx + 3] = excl + v0 + v1 + v2;
  if (tid == 1023) bsum[blockIdx.x] = wsum[15];   // block total
}

__global__ void k_scanB(int* __restrict__ bsum) {
  int lane = threadIdx.x & 63;
  int v = (lane < NBS) ? bsum[lane] : 0;
  int sc = v;
  #pragma unroll
  for (int off = 1; off < 64; off <<= 1) {
    int n = __shfl_up(sc, off);
    if (lane >= off) sc += n;
  }
  if (lane < NBS) bsum[lane] = sc - v;   // exclusive
}

__global__ __launch_bounds__(1024) void k_scanC(int* __restrict__ rowptr,
                                                const int* __restrict__ bsum) {
  int add = bsum[blockIdx.x];
  int idx = blockIdx.x * 4096 + threadIdx.x * 4;
  if (idx     <= NN) rowptr[idx]     += add;
  if (idx + 1 <= NN) rowptr[idx + 1] += add;
  if (idx + 2 <= NN) rowptr[idx + 2] += add;
  if (idx + 3 <= NN) rowptr[idx + 3] += add;
}

__global__ void k_fill(const int* __restrict__ src, const int* __restrict__ dst,
                       const int* __restrict__ rowptr, int* __restrict__ cursor,
                       int* __restrict__ csr) {
  int xcd = blockIdx.x & 7;
  int e = (blockIdx.x >> 3) * 256 + threadIdx.x;
  if (e >= NE) return;
  int d = dst[e];
  if ((unsigned)(d - xcd * NPX) < (unsigned)NPX) {
    int pos = rowptr[d] + atomicAdd(&cursor[d], 1);
    csr[pos] = src[e];
  }
}

// ---------------- weight transpose + bf16 convert ----------------
__global__ void k_wconv(const float* __restrict__ w0, const float* __restrict__ w1,
                        const float* __restrict__ w2, const float* __restrict__ w3,
                        const float* __restrict__ w4, const float* __restrict__ w5,
                        unsigned short* __restrict__ wt) {
  int idx = blockIdx.x * 256 + threadIdx.x;
  if (idx >= 6 * 16384) return;
  int m = idx >> 14, rem = idx & 16383;
  int n = rem >> 7, k = rem & 127;
  const float* W = (m == 0) ? w0 : (m == 1) ? w1 : (m == 2) ? w2
                 : (m == 3) ? w3 : (m == 4) ? w4 : w5;
  wt[idx] = f2bf(W[k * 128 + n]);   // wt[m][n][k] = W[k][n]
}

// ---------------- x -> bf16 ----------------
__global__ void k_xconv(const float* __restrict__ x, unsigned short* __restrict__ xb) {
  int i = blockIdx.x * 256 + threadIdx.x;
  if (i >= NN * DD / 4) return;
  float4 v = ((const float4*)x)[i];
  uint2 p;
  p.x = (unsigned int)f2bf(v.x) | ((unsigned int)f2bf(v.y) << 16);
  p.y = (unsigned int)f2bf(v.z) | ((unsigned int)f2bf(v.w) << 16);
  ((uint2*)xb)[i] = p;
}

// ---------------- fused GIN layer: aggregate + MLP (1 wave / 16 nodes) ----------------
// 6250 blocks x 64 threads. Gather: lane-group kg owns row lrow=it*4+kg;
// 8 rows in flight per round (deg~16 -> ~2 rounds + self vs 5 rounds at
// 4-deep) to compensate the low wave count (6250 waves = 24/CU ceiling)
// with per-wave ILP. fp32 accum -> bf16 -> XOR-swizzled LDS tile
// (16B chunk c of row r at c ^ (r&7)). Then GEMM1, u overwrites tile, GEMM2.
__global__ __launch_bounds__(64) void k_gin(const unsigned short* __restrict__ hb,
                                            const int* __restrict__ rowptr,
                                            const int* __restrict__ csr,
                                            const unsigned short* __restrict__ w1t,
                                            const float* __restrict__ b1,
                                            const unsigned short* __restrict__ w2t,
                                            const float* __restrict__ b2,
                                            unsigned short* __restrict__ hout) {
  __shared__ unsigned short wt_[16 * DD];   // 4 KB, wave-private
  const int lane = threadIdx.x;
  const int r16  = lane & 15;
  const int kg   = lane >> 4;
  const int waveBase = blockIdx.x * 16;
  const uint4* h4 = (const uint4*)hb;

  // ---- phase 1: aggregate ----
  #pragma unroll
  for (int it = 0; it < 4; ++it) {
    const int lrow = it * 4 + kg;
    const int node = waveBase + lrow;
    float acc[8] = {0.f,0.f,0.f,0.f,0.f,0.f,0.f,0.f};
    if (node < NN) {
      addu4(acc, h4[(size_t)node * 16 + r16]);   // self
      int j = rowptr[node];
      const int je = rowptr[node + 1];
      for (; j + 7 < je; j += 8) {
        int s0 = csr[j],     s1 = csr[j + 1], s2 = csr[j + 2], s3 = csr[j + 3];
        int s4 = csr[j + 4], s5 = csr[j + 5], s6 = csr[j + 6], s7 = csr[j + 7];
        uint4 v0 = h4[(size_t)s0 * 16 + r16];
        uint4 v1 = h4[(size_t)s1 * 16 + r16];
        uint4 v2 = h4[(size_t)s2 * 16 + r16];
        uint4 v3 = h4[(size_t)s3 * 16 + r16];
        uint4 v4 = h4[(size_t)s4 * 16 + r16];
        uint4 v5 = h4[(size_t)s5 * 16 + r16];
        uint4 v6 = h4[(size_t)s6 * 16 + r16];
        uint4 v7 = h4[(size_t)s7 * 16 + r16];
        addu4(acc, v0); addu4(acc, v1); addu4(acc, v2); addu4(acc, v3);
        addu4(acc, v4); addu4(acc, v5); addu4(acc, v6); addu4(acc, v7);
      }
      for (; j + 3 < je; j += 4) {
        int s0 = csr[j], s1 = csr[j + 1], s2 = csr[j + 2], s3 = csr[j + 3];
        uint4 v0 = h4[(size_t)s0 * 16 + r16];
        uint4 v1 = h4[(size_t)s1 * 16 + r16];
        uint4 v2 = h4[(size_t)s2 * 16 + r16];
        uint4 v3 = h4[(size_t)s3 * 16 + r16];
        addu4(acc, v0); addu4(acc, v1); addu4(acc, v2); addu4(acc, v3);
      }
      for (; j < je; ++j) addu4(acc, h4[(size_t)csr[j] * 16 + r16]);
    }
    uint4 p;
    p.x = (unsigned int)f2bf(acc[0]) | ((unsigned int)f2bf(acc[1]) << 16);
    p.y = (unsigned int)f2bf(acc[2]) | ((unsigned int)f2bf(acc[3]) << 16);
    p.z = (unsigned int)f2bf(acc[4]) | ((unsigned int)f2bf(acc[5]) << 16);
    p.w = (unsigned int)f2bf(acc[6]) | ((unsigned int)f2bf(acc[7]) << 16);
    *(uint4*)(wt_ + lrow * DD + ((r16 ^ (lrow & 7)) << 3)) = p;
  }
  // wave-private tile: no barrier needed

  // ---- phase 2a: GEMM1  u = ReLU(t @ W1 + b1) ----
  f32x4 acc[8];
  #pragma unroll
  for (int nb = 0; nb < 8; ++nb) acc[nb] = (f32x4){0.f, 0.f, 0.f, 0.f};
  #pragma unroll
  for (int s = 0; s < 4; ++s) {
    ABu au;
    au.q = *(const uint4*)(wt_ + r16 * DD + ((((s << 2) + kg) ^ (r16 & 7)) << 3));
    #pragma unroll
    for (int nb = 0; nb < 8; ++nb) {
      ABu bu; bu.q = *(const uint4*)(w1t + (nb * 16 + r16) * DD + s * 32 + kg * 8);
      acc[nb] = __builtin_amdgcn_mfma_f32_16x16x32_bf16(au.v, bu.v, acc[nb], 0, 0, 0);
    }
  }
  #pragma unroll
  for (int nb = 0; nb < 8; ++nb) {
    int n = nb * 16 + r16;
    float bias = b1[n];
    #pragma unroll
    for (int reg = 0; reg < 4; ++reg) {
      int urow = (kg << 2) + reg;
      float v = acc[nb][reg] + bias;
      v = v > 0.f ? v : 0.f;
      wt_[urow * DD + ((((n >> 3) ^ (urow & 7)) << 3) | (n & 7))] = f2bf(v);
    }
  }

  // ---- phase 2b: GEMM2  hout = u @ W2 + b2 ----
  #pragma unroll
  for (int nb = 0; nb < 8; ++nb) acc[nb] = (f32x4){0.f, 0.f, 0.f, 0.f};
  #pragma unroll
  for (int s = 0; s < 4; ++s) {
    ABu au;
    au.q = *(const uint4*)(wt_ + r16 * DD + ((((s << 2) + kg) ^ (r16 & 7)) << 3));
    #pragma unroll
    for (int nb = 0; nb < 8; ++nb) {
      ABu bu; bu.q = *(const uint4*)(w2t + (nb * 16 + r16) * DD + s * 32 + kg * 8);
      acc[nb] = __builtin_amdgcn_mfma_f32_16x16x32_bf16(au.v, bu.v, acc[nb], 0, 0, 0);
    }
  }
  #pragma unroll
  for (int reg = 0; reg < 4; ++reg) {
    int row = waveBase + (kg << 2) + reg;
    if (row < NN) {
      #pragma unroll
      for (int nb = 0; nb < 8; ++nb) {
        int n = nb * 16 + r16;
        hout[row * DD + n] = f2bf(acc[nb][reg] + b2[n]);
      }
    }
  }
}

// ---------------- fused pooling: one block per graph (batch sorted) ----------------
__global__ __launch_bounds__(256) void k_pool(const unsigned short* __restrict__ hb,
                                              const int* __restrict__ batch,
                                              float* __restrict__ out) {
  const int g  = blockIdx.x;
  const int f2 = threadIdx.x & 63;
  const int rp = threadIdx.x >> 6;
  int lo = 0, hi = NN;
  while (lo < hi) { int m = (lo + hi) >> 1; if (batch[m] < g) lo = m + 1; else hi = m; }
  const int start = lo;
  hi = NN;
  while (lo < hi) { int m = (lo + hi) >> 1; if (batch[m] < g + 1) lo = m + 1; else hi = m; }
  const int end = lo;

  const unsigned int* h32 = (const unsigned int*)hb;
  float2 acc = {0.f, 0.f};
  int i = start + rp;
  for (; i + 4 < end; i += 8) {
    float2 a = bfu(h32[(size_t)i * 64 + f2]);
    float2 b = bfu(h32[(size_t)(i + 4) * 64 + f2]);
    acc.x += a.x + b.x; acc.y += a.y + b.y;
  }
  for (; i < end; i += 4) {
    float2 a = bfu(h32[(size_t)i * 64 + f2]);
    acc.x += a.x; acc.y += a.y;
  }

  __shared__ float2 part[4][64];
  part[rp][f2] = acc;
  __syncthreads();
  if (rp == 0) {
    float2 t0 = part[0][f2], t1 = part[1][f2], t2 = part[2][f2], t3 = part[3][f2];
    float inv = 1.0f / (float)max(end - start, 1);
    out[g * DD + 2 * f2]     = (t0.x + t1.x + t2.x + t3.x) * inv;
    out[g * DD + 2 * f2 + 1] = (t0.y + t1.y + t2.y + t3.y) * inv;
  }
}

// ---------------- launch ----------------
extern "C" void kernel_launch(void* const* d_in, const int* in_sizes, int n_in,
                              void* d_out, int out_size, void* d_ws, size_t ws_size,
                              hipStream_t stream) {
  const float* x    = (const float*)d_in[0];
  const int* ei     = (const int*)d_in[1];
  const int* src    = ei;
  const int* dst    = ei + NE;
  const int* batch  = (const int*)d_in[2];

  char* ws = (char*)d_ws;
  size_t off = 0;
  auto alloc = [&](size_t bytes) { char* p = ws + off; off = (off + bytes + 255) & ~(size_t)255; return p; };

  int*  deg    = (int*)alloc(2 * NN * 4);       // deg + cursor contiguous
  int*  cursor = deg + NN;
  int*  rowptr = (int*)alloc((NN + 1) * 4);
  int*  bsum   = (int*)alloc(NBS * 4);
  int*  csr    = (int*)alloc(NE * 4);
  unsigned short* wt = (unsigned short*)alloc(6 * 16384 * 2);
  unsigned short* xb = (unsigned short*)alloc((size_t)NN * DD * 2);
  unsigned short* hA = (unsigned short*)alloc((size_t)NN * DD * 2);
  unsigned short* hB = (unsigned short*)alloc((size_t)NN * DD * 2);

  hipMemsetAsync(deg, 0, 2 * NN * 4, stream);

  k_wconv<<<(6 * 16384 + 255) / 256, 256, 0, stream>>>(
      (const float*)d_in[3], (const float*)d_in[5],
      (const float*)d_in[7], (const float*)d_in[9],
      (const float*)d_in[11], (const float*)d_in[13], wt);
  k_xconv<<<(NN * DD / 4 + 255) / 256, 256, 0, stream>>>(x, xb);

  const int echunks = (NE + 255) / 256;
  k_count<<<8 * echunks, 256, 0, stream>>>(dst, deg);
  k_scanA<<<NBS, 1024, 0, stream>>>(deg, rowptr, bsum);
  k_scanB<<<1, 64, 0, stream>>>(bsum);
  k_scanC<<<NBS, 1024, 0, stream>>>(rowptr, bsum);
  k_fill<<<8 * echunks, 256, 0, stream>>>(src, dst, rowptr, cursor, csr);

  const unsigned short* hin = xb;
  unsigned short* houts[3] = {hA, hB, hA};
  for (int l = 0; l < 3; ++l) {
    k_gin<<<(NN + 15) / 16, 64, 0, stream>>>(
        hin, rowptr, csr,
        wt + (2 * l) * 16384, (const float*)d_in[4 + 4 * l],
        wt + (2 * l + 1) * 16384, (const float*)d_in[6 + 4 * l], houts[l]);
    hin = houts[l];
  }

  k_pool<<<NG, 256, 0, stream>>>(hin, batch, (float*)d_out);
}

// Round 14
// 589.022 us; speedup vs baseline: 1.0799x; 1.0399x over previous
//
#include <hip/hip_runtime.h>
#include <stdint.h>

#define NN 100000
#define NE 1600000
#define DD 128
#define NG 128
#define NPX 12500     // nodes per XCD partition (8 * 12500 = 100000)
#define NBS 25        // scan blocks: 25 * 4096 > NN+1

using f32x4  = __attribute__((ext_vector_type(4))) float;
using bf16x8 = __attribute__((ext_vector_type(8))) __bf16;

__device__ __forceinline__ unsigned short f2bf(float f) {
  unsigned int u = __builtin_bit_cast(unsigned int, f);
  u = (u + 0x7FFFu + ((u >> 16) & 1u)) >> 16;
  return (unsigned short)u;
}

__device__ __forceinline__ float2 bfu(unsigned int u) {
  float2 r;
  r.x = __builtin_bit_cast(float, u << 16);
  r.y = __builtin_bit_cast(float, u & 0xffff0000u);
  return r;
}

__device__ __forceinline__ void addu4(float* a, uint4 v) {
  float2 p0 = bfu(v.x), p1 = bfu(v.y), p2 = bfu(v.z), p3 = bfu(v.w);
  a[0] += p0.x; a[1] += p0.y; a[2] += p1.x; a[3] += p1.y;
  a[4] += p2.x; a[5] += p2.y; a[6] += p3.x; a[7] += p3.y;
}

union ABu { uint4 q; bf16x8 v; };

// ---------------- CSR build (XCD-partitioned scatter) ----------------
__global__ void k_count(const int* __restrict__ dst, int* __restrict__ deg) {
  int xcd = blockIdx.x & 7;
  int e = (blockIdx.x >> 3) * 256 + threadIdx.x;
  if (e >= NE) return;
  int d = dst[e];
  if ((unsigned)(d - xcd * NPX) < (unsigned)NPX) atomicAdd(&deg[d], 1);
}

// ---- 3-kernel scan: rowptr = exclusive_scan(deg), rowptr[NN] = total ----
__global__ __launch_bounds__(1024) void k_scanA(const int* __restrict__ deg,
                                                int* __restrict__ rowptr,
                                                int* __restrict__ bsum) {
  __shared__ int wsum[16];
  const int tid = threadIdx.x, wid = tid >> 6, lane = tid & 63;
  int idx = blockIdx.x * 4096 + tid * 4;
  int v0 = (idx + 0 < NN) ? deg[idx + 0] : 0;
  int v1 = (idx + 1 < NN) ? deg[idx + 1] : 0;
  int v2 = (idx + 2 < NN) ? deg[idx + 2] : 0;
  int v3 = (idx + 3 < NN) ? deg[idx + 3] : 0;
  int tsum = v0 + v1 + v2 + v3;
  int sc = tsum;
  #pragma unroll
  for (int off = 1; off < 64; off <<= 1) {
    int n = __shfl_up(sc, off);
    if (lane >= off) sc += n;
  }
  if (lane == 63) wsum[wid] = sc;
  __syncthreads();
  if (wid == 0 && lane < 16) {
    int w = wsum[lane];
    #pragma unroll
    for (int off = 1; off < 16; off <<= 1) {
      int n = __shfl_up(w, off);
      if (lane >= off) w += n;
    }
    wsum[lane] = w;
  }
  __syncthreads();
  int excl = (wid ? wsum[wid - 1] : 0) + sc - tsum;
  if (idx     <= NN) rowptr[idx]     = excl;
  if (idx + 1 <= NN) rowptr[idx + 1] = excl + v0;
  if (idx + 2 <= NN) rowptr[idx + 2] = excl + v0 + v1;
  if (idx + 3 <= NN) rowptr[idx + 3] = excl + v0 + v1 + v2;
  if (tid == 1023) bsum[blockIdx.x] = wsum[15];   // block total
}

__global__ void k_scanB(int* __restrict__ bsum) {
  int lane = threadIdx.x & 63;
  int v = (lane < NBS) ? bsum[lane] : 0;
  int sc = v;
  #pragma unroll
  for (int off = 1; off < 64; off <<= 1) {
    int n = __shfl_up(sc, off);
    if (lane >= off) sc += n;
  }
  if (lane < NBS) bsum[lane] = sc - v;   // exclusive
}

__global__ __launch_bounds__(1024) void k_scanC(int* __restrict__ rowptr,
                                                const int* __restrict__ bsum) {
  int add = bsum[blockIdx.x];
  int idx = blockIdx.x * 4096 + threadIdx.x * 4;
  if (idx     <= NN) rowptr[idx]     += add;
  if (idx + 1 <= NN) rowptr[idx + 1] += add;
  if (idx + 2 <= NN) rowptr[idx + 2] += add;
  if (idx + 3 <= NN) rowptr[idx + 3] += add;
}

__global__ void k_fill(const int* __restrict__ src, const int* __restrict__ dst,
                       const int* __restrict__ rowptr, int* __restrict__ cursor,
                       int* __restrict__ csr) {
  int xcd = blockIdx.x & 7;
  int e = (blockIdx.x >> 3) * 256 + threadIdx.x;
  if (e >= NE) return;
  int d = dst[e];
  if ((unsigned)(d - xcd * NPX) < (unsigned)NPX) {
    int pos = rowptr[d] + atomicAdd(&cursor[d], 1);
    csr[pos] = src[e];
  }
}

// ---------------- weight transpose + bf16 convert ----------------
__global__ void k_wconv(const float* __restrict__ w0, const float* __restrict__ w1,
                        const float* __restrict__ w2, const float* __restrict__ w3,
                        const float* __restrict__ w4, const float* __restrict__ w5,
                        unsigned short* __restrict__ wt) {
  int idx = blockIdx.x * 256 + threadIdx.x;
  if (idx >= 6 * 16384) return;
  int m = idx >> 14, rem = idx & 16383;
  int n = rem >> 7, k = rem & 127;
  const float* W = (m == 0) ? w0 : (m == 1) ? w1 : (m == 2) ? w2
                 : (m == 3) ? w3 : (m == 4) ? w4 : w5;
  wt[idx] = f2bf(W[k * 128 + n]);   // wt[m][n][k] = W[k][n]
}

// ---------------- x -> bf16 ----------------
__global__ void k_xconv(const float* __restrict__ x, unsigned short* __restrict__ xb) {
  int i = blockIdx.x * 256 + threadIdx.x;
  if (i >= NN * DD / 4) return;
  float4 v = ((const float4*)x)[i];
  uint2 p;
  p.x = (unsigned int)f2bf(v.x) | ((unsigned int)f2bf(v.y) << 16);
  p.y = (unsigned int)f2bf(v.z) | ((unsigned int)f2bf(v.w) << 16);
  ((uint2*)xb)[i] = p;
}

// ---------------- fused GIN layer: aggregate + MLP ----------------
// 6250 blocks x 256 threads (4 waves) per 16 nodes -> 25000 gather waves
// (4x R13: the wave-count ceiling was the binding constraint, not per-wave
// ILP). Phase 1: each of 16 lane-groups (wave wv, group kg) gathers ONE row
// lrow = wv*4+kg into the block-shared XOR-swizzled LDS tile [16][128]
// (16B chunk c of row r at c ^ (r&7)); 8 neighbor rows in flight.
// Phase 2: wave wv computes n-blocks {2wv, 2wv+1}: GEMM1 -> u overwrites
// tile (disjoint columns per wave) -> barrier -> GEMM2 -> bf16 store.
__global__ __launch_bounds__(256) void k_gin(const unsigned short* __restrict__ hb,
                                             const int* __restrict__ rowptr,
                                             const int* __restrict__ csr,
                                             const unsigned short* __restrict__ w1t,
                                             const float* __restrict__ b1,
                                             const unsigned short* __restrict__ w2t,
                                             const float* __restrict__ b2,
                                             unsigned short* __restrict__ hout) {
  __shared__ unsigned short wt_[16 * DD];   // 4 KB, block-shared
  const int wv   = threadIdx.x >> 6;
  const int lane = threadIdx.x & 63;
  const int r16  = lane & 15;
  const int kg   = lane >> 4;
  const int blockBase = blockIdx.x * 16;
  const uint4* h4 = (const uint4*)hb;

  // ---- phase 1: each lane-group gathers one row ----
  {
    const int lrow = wv * 4 + kg;          // 0..15
    const int node = blockBase + lrow;
    float acc[8] = {0.f,0.f,0.f,0.f,0.f,0.f,0.f,0.f};
    if (node < NN) {
      addu4(acc, h4[(size_t)node * 16 + r16]);   // self
      int j = rowptr[node];
      const int je = rowptr[node + 1];
      for (; j + 7 < je; j += 8) {
        int s0 = csr[j],     s1 = csr[j + 1], s2 = csr[j + 2], s3 = csr[j + 3];
        int s4 = csr[j + 4], s5 = csr[j + 5], s6 = csr[j + 6], s7 = csr[j + 7];
        uint4 v0 = h4[(size_t)s0 * 16 + r16];
        uint4 v1 = h4[(size_t)s1 * 16 + r16];
        uint4 v2 = h4[(size_t)s2 * 16 + r16];
        uint4 v3 = h4[(size_t)s3 * 16 + r16];
        uint4 v4 = h4[(size_t)s4 * 16 + r16];
        uint4 v5 = h4[(size_t)s5 * 16 + r16];
        uint4 v6 = h4[(size_t)s6 * 16 + r16];
        uint4 v7 = h4[(size_t)s7 * 16 + r16];
        addu4(acc, v0); addu4(acc, v1); addu4(acc, v2); addu4(acc, v3);
        addu4(acc, v4); addu4(acc, v5); addu4(acc, v6); addu4(acc, v7);
      }
      for (; j + 3 < je; j += 4) {
        int s0 = csr[j], s1 = csr[j + 1], s2 = csr[j + 2], s3 = csr[j + 3];
        uint4 v0 = h4[(size_t)s0 * 16 + r16];
        uint4 v1 = h4[(size_t)s1 * 16 + r16];
        uint4 v2 = h4[(size_t)s2 * 16 + r16];
        uint4 v3 = h4[(size_t)s3 * 16 + r16];
        addu4(acc, v0); addu4(acc, v1); addu4(acc, v2); addu4(acc, v3);
      }
      for (; j < je; ++j) addu4(acc, h4[(size_t)csr[j] * 16 + r16]);
    }
    uint4 p;
    p.x = (unsigned int)f2bf(acc[0]) | ((unsigned int)f2bf(acc[1]) << 16);
    p.y = (unsigned int)f2bf(acc[2]) | ((unsigned int)f2bf(acc[3]) << 16);
    p.z = (unsigned int)f2bf(acc[4]) | ((unsigned int)f2bf(acc[5]) << 16);
    p.w = (unsigned int)f2bf(acc[6]) | ((unsigned int)f2bf(acc[7]) << 16);
    *(uint4*)(wt_ + lrow * DD + ((r16 ^ (lrow & 7)) << 3)) = p;
  }
  __syncthreads();

  // ---- phase 2a: GEMM1 (wave wv owns n-blocks 2wv, 2wv+1) ----
  f32x4 acc[2];
  acc[0] = (f32x4){0.f, 0.f, 0.f, 0.f};
  acc[1] = (f32x4){0.f, 0.f, 0.f, 0.f};
  #pragma unroll
  for (int s = 0; s < 4; ++s) {
    ABu au;
    au.q = *(const uint4*)(wt_ + r16 * DD + ((((s << 2) + kg) ^ (r16 & 7)) << 3));
    #pragma unroll
    for (int q = 0; q < 2; ++q) {
      int nb = wv * 2 + q;
      ABu bu; bu.q = *(const uint4*)(w1t + (nb * 16 + r16) * DD + s * 32 + kg * 8);
      acc[q] = __builtin_amdgcn_mfma_f32_16x16x32_bf16(au.v, bu.v, acc[q], 0, 0, 0);
    }
  }
  __syncthreads();   // all A-reads done before u overwrites the tile
  #pragma unroll
  for (int q = 0; q < 2; ++q) {
    int nb = wv * 2 + q;
    int n = nb * 16 + r16;
    float bias = b1[n];
    #pragma unroll
    for (int reg = 0; reg < 4; ++reg) {
      int urow = (kg << 2) + reg;
      float v = acc[q][reg] + bias;
      v = v > 0.f ? v : 0.f;
      wt_[urow * DD + ((((n >> 3) ^ (urow & 7)) << 3) | (n & 7))] = f2bf(v);
    }
  }
  __syncthreads();

  // ---- phase 2b: GEMM2 ----
  acc[0] = (f32x4){0.f, 0.f, 0.f, 0.f};
  acc[1] = (f32x4){0.f, 0.f, 0.f, 0.f};
  #pragma unroll
  for (int s = 0; s < 4; ++s) {
    ABu au;
    au.q = *(const uint4*)(wt_ + r16 * DD + ((((s << 2) + kg) ^ (r16 & 7)) << 3));
    #pragma unroll
    for (int q = 0; q < 2; ++q) {
      int nb = wv * 2 + q;
      ABu bu; bu.q = *(const uint4*)(w2t + (nb * 16 + r16) * DD + s * 32 + kg * 8);
      acc[q] = __builtin_amdgcn_mfma_f32_16x16x32_bf16(au.v, bu.v, acc[q], 0, 0, 0);
    }
  }
  #pragma unroll
  for (int reg = 0; reg < 4; ++reg) {
    int row = blockBase + (kg << 2) + reg;
    if (row < NN) {
      #pragma unroll
      for (int q = 0; q < 2; ++q) {
        int n = (wv * 2 + q) * 16 + r16;
        hout[row * DD + n] = f2bf(acc[q][reg] + b2[n]);
      }
    }
  }
}

// ---------------- fused pooling: one block per graph (batch sorted) ----------------
__global__ __launch_bounds__(256) void k_pool(const unsigned short* __restrict__ hb,
                                              const int* __restrict__ batch,
                                              float* __restrict__ out) {
  const int g  = blockIdx.x;
  const int f2 = threadIdx.x & 63;
  const int rp = threadIdx.x >> 6;
  int lo = 0, hi = NN;
  while (lo < hi) { int m = (lo + hi) >> 1; if (batch[m] < g) lo = m + 1; else hi = m; }
  const int start = lo;
  hi = NN;
  while (lo < hi) { int m = (lo + hi) >> 1; if (batch[m] < g + 1) lo = m + 1; else hi = m; }
  const int end = lo;

  const unsigned int* h32 = (const unsigned int*)hb;
  float2 acc = {0.f, 0.f};
  int i = start + rp;
  for (; i + 4 < end; i += 8) {
    float2 a = bfu(h32[(size_t)i * 64 + f2]);
    float2 b = bfu(h32[(size_t)(i + 4) * 64 + f2]);
    acc.x += a.x + b.x; acc.y += a.y + b.y;
  }
  for (; i < end; i += 4) {
    float2 a = bfu(h32[(size_t)i * 64 + f2]);
    acc.x += a.x; acc.y += a.y;
  }

  __shared__ float2 part[4][64];
  part[rp][f2] = acc;
  __syncthreads();
  if (rp == 0) {
    float2 t0 = part[0][f2], t1 = part[1][f2], t2 = part[2][f2], t3 = part[3][f2];
    float inv = 1.0f / (float)max(end - start, 1);
    out[g * DD + 2 * f2]     = (t0.x + t1.x + t2.x + t3.x) * inv;
    out[g * DD + 2 * f2 + 1] = (t0.y + t1.y + t2.y + t3.y) * inv;
  }
}

// ---------------- launch ----------------
extern "C" void kernel_launch(void* const* d_in, const int* in_sizes, int n_in,
                              void* d_out, int out_size, void* d_ws, size_t ws_size,
                              hipStream_t stream) {
  const float* x    = (const float*)d_in[0];
  const int* ei     = (const int*)d_in[1];
  const int* src    = ei;
  const int* dst    = ei + NE;
  const int* batch  = (const int*)d_in[2];

  char* ws = (char*)d_ws;
  size_t off = 0;
  auto alloc = [&](size_t bytes) { char* p = ws + off; off = (off + bytes + 255) & ~(size_t)255; return p; };

  int*  deg    = (int*)alloc(2 * NN * 4);       // deg + cursor contiguous
  int*  cursor = deg + NN;
  int*  rowptr = (int*)alloc((NN + 1) * 4);
  int*  bsum   = (int*)alloc(NBS * 4);
  int*  csr    = (int*)alloc(NE * 4);
  unsigned short* wt = (unsigned short*)alloc(6 * 16384 * 2);
  unsigned short* xb = (unsigned short*)alloc((size_t)NN * DD * 2);
  unsigned short* hA = (unsigned short*)alloc((size_t)NN * DD * 2);
  unsigned short* hB = (unsigned short*)alloc((size_t)NN * DD * 2);

  hipMemsetAsync(deg, 0, 2 * NN * 4, stream);

  k_wconv<<<(6 * 16384 + 255) / 256, 256, 0, stream>>>(
      (const float*)d_in[3], (const float*)d_in[5],
      (const float*)d_in[7], (const float*)d_in[9],
      (const float*)d_in[11], (const float*)d_in[13], wt);
  k_xconv<<<(NN * DD / 4 + 255) / 256, 256, 0, stream>>>(x, xb);

  const int echunks = (NE + 255) / 256;
  k_count<<<8 * echunks, 256, 0, stream>>>(dst, deg);
  k_scanA<<<NBS, 1024, 0, stream>>>(deg, rowptr, bsum);
  k_scanB<<<1, 64, 0, stream>>>(bsum);
  k_scanC<<<NBS, 1024, 0, stream>>>(rowptr, bsum);
  k_fill<<<8 * echunks, 256, 0, stream>>>(src, dst, rowptr, cursor, csr);

  const unsigned short* hin = xb;
  unsigned short* houts[3] = {hA, hB, hA};
  for (int l = 0; l < 3; ++l) {
    k_gin<<<(NN + 15) / 16, 256, 0, stream>>>(
        hin, rowptr, csr,
        wt + (2 * l) * 16384, (const float*)d_in[4 + 4 * l],
        wt + (2 * l + 1) * 16384, (const float*)d_in[6 + 4 * l], houts[l]);
    hin = houts[l];
  }

  k_pool<<<NG, 256, 0, stream>>>(hin, batch, (float*)d_out);
}